// Round 9
// baseline (243.926 us; speedup 1.0000x reference)
//
#include <hip/hip_runtime.h>
#include <hip/hip_bf16.h>

typedef unsigned int uint;
typedef unsigned short ushort;
typedef __attribute__((ext_vector_type(8))) short bfrag_t;
typedef __attribute__((ext_vector_type(4))) short s4_t;
typedef __attribute__((ext_vector_type(4))) float f4_t;
typedef __attribute__((ext_vector_type(2))) float f2_t;

#define EPSV 1e-5f

__device__ __forceinline__ float4 ld4(const float* p) { return *(const float4*)p; }
__device__ __forceinline__ void st4(float* p, float4 v) { *(float4*)p = v; }

__device__ __forceinline__ ushort f2bf(float f) {
    union { float f; uint u; } v; v.f = f;
    uint r = v.u + 0x7fffu + ((v.u >> 16) & 1u);
    return (ushort)(r >> 16);
}
__device__ __forceinline__ float bf2f(ushort s) {
    union { uint u; float f; } v; v.u = ((uint)s) << 16;
    return v.f;
}
__device__ __forceinline__ float bfhi(uint u) { union { uint u; float f; } v; v.u = u & 0xffff0000u; return v.f; }
__device__ __forceinline__ float bflo(uint u) { union { uint u; float f; } v; v.u = u << 16; return v.f; }
__device__ __forceinline__ uint pk2(float a, float b) { return (uint)f2bf(a) | ((uint)f2bf(b) << 16); }
__device__ __forceinline__ uint pkrn(float a, float b) {
    union { __hip_bfloat162 h; uint u; } v;
    v.h = __float22bfloat162_rn(make_float2(a, b));
    return v.u;
}

// One dispatch for all preprocessing:
//   bid <  512: wT[(k*256+co)*256+ci] = bf16(w_def[co][ci][k])
//   512..575  : wO[(k*32+co)*256+ci]  = co<18 ? bf16(w_off[co][ci][k]) : 0  (+ gnacc zeroing)
//   bid >= 576: NCHW fp32 -> NHWC bf16 transpose (1024 blocks)
__global__ __launch_bounds__(256) void prep_all(const float* __restrict__ wd1, const float* __restrict__ wd2,
                                                const float* __restrict__ wo1, const float* __restrict__ wo2,
                                                const float* __restrict__ x,
                                                ushort* __restrict__ oT1, ushort* __restrict__ oT2,
                                                ushort* __restrict__ oO1, ushort* __restrict__ oO2,
                                                ushort* __restrict__ xb, float* __restrict__ gnacc) {
    __shared__ float lds[64][65];
    int bid = blockIdx.x;
    int tid = threadIdx.x;
    if (bid < 512) {
        int co = bid & 255;
        int sel = bid >> 8;
        const float* w = sel ? wd2 : wd1;
        ushort* o = sel ? oT2 : oT1;
        const float* p = w + (co * 256 + tid) * 9;
        float v[9];
#pragma unroll
        for (int k = 0; k < 9; ++k) v[k] = p[k];
#pragma unroll
        for (int k = 0; k < 9; ++k) o[(k * 256 + co) * 256 + tid] = f2bf(v[k]);
    } else if (bid < 576) {
        int idx = bid - 512;
        int co = idx & 31;
        int sel = idx >> 5;
        const float* w = sel ? wo2 : wo1;
        ushort* o = sel ? oO2 : oO1;
        float v[9] = {0.f,0.f,0.f,0.f,0.f,0.f,0.f,0.f,0.f};
        if (co < 18) {
            const float* p = w + (co * 256 + tid) * 9;
#pragma unroll
            for (int k = 0; k < 9; ++k) v[k] = p[k];
        }
#pragma unroll
        for (int k = 0; k < 9; ++k) o[(k * 32 + co) * 256 + tid] = f2bf(v[k]);
        if (idx == 0) { gnacc[tid] = 0.f; gnacc[256 + tid] = 0.f; }
    } else {
        int b2 = bid - 576;                 // b*256 + y*4 + cb
        int cb = b2 & 3, y = (b2 >> 2) & 63, b = b2 >> 8;
        int c0 = cb << 6;
#pragma unroll
        for (int i = 0; i < 4; ++i) {
            int q = tid + (i << 8);
            int c_l = q >> 4, x4 = (q & 15) << 2;
            float4 v = ld4(&x[((b * 256 + c0 + c_l) << 12) + (y << 6) + x4]);
            lds[c_l][x4 + 0] = v.x; lds[c_l][x4 + 1] = v.y; lds[c_l][x4 + 2] = v.z; lds[c_l][x4 + 3] = v.w;
        }
        __syncthreads();
#pragma unroll
        for (int i = 0; i < 4; ++i) {
            int q = tid + (i << 8);
            int x_l = q >> 4, c4 = (q & 15) << 2;
            s4_t v;
            v.x = (short)f2bf(lds[c4 + 0][x_l]); v.y = (short)f2bf(lds[c4 + 1][x_l]);
            v.z = (short)f2bf(lds[c4 + 2][x_l]); v.w = (short)f2bf(lds[c4 + 3][x_l]);
            *(s4_t*)&xb[(((b << 12) + (y << 6) + x_l) << 8) + c0 + c4] = v;
        }
    }
}

// Offset conv (r8 geometry, now templated on FUSE): 512 thr / 64-px row tile /
// grid 256; 8 waves k-split 32-ci. FUSE=1 applies GN1+ReLU on the A-load
// (channel blocks align with GN groups: 8 ch/group), replacing the separate
// gn_apply pass. Same bf16 RNE rounding as the old standalone kernel.
template<int FUSE>
__global__ __launch_bounds__(512, 2) void offconv8(const ushort* __restrict__ xb, const float* __restrict__ gnacc,
                                                   const float* __restrict__ gamma, const float* __restrict__ beta,
                                                   const ushort* __restrict__ wO,
                                                   const float* __restrict__ bias, float* __restrict__ offb) {
    __shared__ float red2[8][64][33];       // +1 pad on elem dim
    int bidx = blockIdx.x;                  // 256
    int tile = (bidx & 7) * 32 + (bidx >> 3);   // XCD-contiguous px regions
    int px0 = tile << 6;
    int b = tile >> 6;                      // tile = b*64 + y
    int y = tile & 63;
    int tid = threadIdx.x;
    int wave = tid >> 6, lane = tid & 63;
    int lr = lane & 15, lq = lane >> 4;
    int cio = (wave << 5) + (lq << 3);      // this lane's 8-ci offset within 256

    float s8[8], t8[8];
    if (FUSE) {
        int g = cio >> 3;                   // 8 ch/group: this lane's block = one group
        float2 a = *(const float2*)(gnacc + ((b << 5) + g) * 2);
        float mean = a.x * (1.f / 32768.f);
        float var = fmaxf(a.y * (1.f / 32768.f) - mean * mean, 0.f);
        float rstd = rsqrtf(var + EPSV);
#pragma unroll
        for (int j = 0; j < 8; ++j) {
            float ga = gamma[cio + j];
            s8[j] = ga * rstd;
            t8[j] = beta[cio + j] - mean * s8[j];
        }
    }

    f4_t acc[4][2];
#pragma unroll
    for (int m = 0; m < 4; ++m)
#pragma unroll
        for (int n = 0; n < 2; ++n) acc[m][n] = (f4_t){0.f,0.f,0.f,0.f};

#pragma unroll
    for (int tap = 0; tap < 9; ++tap) {
        int ky = tap / 3, kx = tap - ky * 3;
        int yy = y + ky - 1;
        if ((uint)yy < 64u) {               // wave-uniform row validity
            const ushort* wrow = wO + ((tap << 5) << 8) + cio;
            bfrag_t b0 = *(const bfrag_t*)(wrow + (lr << 8));
            bfrag_t b1 = *(const bfrag_t*)(wrow + ((16 + lr) << 8));
            const ushort* arow = xb + (((b << 6) + yy) << 14) + cio;   // row base (x=0)
#pragma unroll
            for (int m = 0; m < 4; ++m) {
                int xx = (m << 4) + lr + kx - 1;
                bfrag_t afr = (bfrag_t){0,0,0,0,0,0,0,0};
                if ((uint)xx < 64u) {
                    if (FUSE) {
                        uint4 raw = *(const uint4*)(arow + (xx << 8));
                        union { uint4 u; bfrag_t f; } cv;
                        cv.u.x = pkrn(fmaxf(s8[0]*bflo(raw.x)+t8[0], 0.f), fmaxf(s8[1]*bfhi(raw.x)+t8[1], 0.f));
                        cv.u.y = pkrn(fmaxf(s8[2]*bflo(raw.y)+t8[2], 0.f), fmaxf(s8[3]*bfhi(raw.y)+t8[3], 0.f));
                        cv.u.z = pkrn(fmaxf(s8[4]*bflo(raw.z)+t8[4], 0.f), fmaxf(s8[5]*bfhi(raw.z)+t8[5], 0.f));
                        cv.u.w = pkrn(fmaxf(s8[6]*bflo(raw.w)+t8[6], 0.f), fmaxf(s8[7]*bfhi(raw.w)+t8[7], 0.f));
                        afr = cv.f;
                    } else {
                        afr = *(const bfrag_t*)(arow + (xx << 8));
                    }
                }
                acc[m][0] = __builtin_amdgcn_mfma_f32_16x16x32_bf16(afr, b0, acc[m][0], 0, 0, 0);
                acc[m][1] = __builtin_amdgcn_mfma_f32_16x16x32_bf16(afr, b1, acc[m][1], 0, 0, 0);
            }
        }
    }
#pragma unroll
    for (int m = 0; m < 4; ++m)
#pragma unroll
        for (int n = 0; n < 2; ++n)
#pragma unroll
            for (int r = 0; r < 4; ++r)
                red2[wave][lane][(m << 3) + (n << 2) + r] = acc[m][n][r];
    __syncthreads();
#pragma unroll
    for (int e = 0; e < 4; ++e) {
        int oi = tid + (e << 9);            // 0..2047 = 64px x 32co
        int px = oi >> 5, co = oi & 31;
        int m = px >> 4, w4 = px & 15;
        int lanes = ((w4 >> 2) << 4) + (co & 15);
        int elem = (m << 3) + ((co >> 4) << 2) + (w4 & 3);
        float v = 0.f;
#pragma unroll
        for (int w = 0; w < 8; ++w) v += red2[w][lanes][elem];
        if (co < 18) offb[(px0 + px) * 18 + co] = v + bias[co];
    }
}

// Deformable conv (r6-verified structure, frozen; templated on FUSE).
// FUSE=1: gather reads raw t1b and applies GN1+ReLU in-register before the
// bilinear combine (per-lane 8-ch blocks = GN groups; 64 const VGPRs).
// r7 lesson: do NOT touch the issue order / barriers — locally optimal.
template<int FUSE>
__global__ __launch_bounds__(512, 2) void deform_mfma(const ushort* __restrict__ xb, const float* __restrict__ gnin,
                                                      const float* __restrict__ gamma, const float* __restrict__ beta,
                                                      const float* __restrict__ offb,
                                                      const ushort* __restrict__ wT, ushort* __restrict__ outb,
                                                      float* __restrict__ gnacc) {
    __shared__ short As[2][16384];     // 2 x 32KB
    __shared__ float red[64];

    int bidx = blockIdx.x;             // 256 tiles
    int tile = (bidx & 7) * 32 + (bidx >> 3);   // XCD-contiguous px regions
    int px0 = tile << 6;
    int bb = px0 >> 12;

    int tid = threadIdx.x;
    int wave = tid >> 6;               // 0..7
    int lane = tid & 63;
    int lr = lane & 15, lq = lane >> 4;

    if (tid < 64) red[tid] = 0.f;

    // gather role: 8 lanes per pixel (64 px x 8 = 512 thr)
    int gpx = tid >> 3;                // 0..63
    int gl = tid & 7;                  // 16B lane within 128B segment
    int pxg = px0 + gpx;
    int gy = (pxg >> 6) & 63, gx = pxg & 63;
    int gbase = (pxg >> 12) << 12;
    const float* offp = offb + pxg * 18;

    // fused-GN constants: q[corner][u] covers channels u*64+gl*8 .. +8 = group u*8+gl
    f2_t s2[4][4], t2[4][4];
    if (FUSE) {
#pragma unroll
        for (int u = 0; u < 4; ++u) {
            int g = (u << 3) + gl;
            float2 a = *(const float2*)(gnin + ((bb << 5) + g) * 2);
            float mean = a.x * (1.f / 32768.f);
            float var = fmaxf(a.y * (1.f / 32768.f) - mean * mean, 0.f);
            float rstd = rsqrtf(var + EPSV);
            int c0 = (u << 6) + (gl << 3);
            float4 ga0 = ld4(&gamma[c0]), ga1 = ld4(&gamma[c0 + 4]);
            float4 be0 = ld4(&beta[c0]),  be1 = ld4(&beta[c0 + 4]);
            s2[u][0] = (f2_t){ga0.x * rstd, ga0.y * rstd};
            s2[u][1] = (f2_t){ga0.z * rstd, ga0.w * rstd};
            s2[u][2] = (f2_t){ga1.x * rstd, ga1.y * rstd};
            s2[u][3] = (f2_t){ga1.z * rstd, ga1.w * rstd};
            t2[u][0] = (f2_t){be0.x - mean * s2[u][0].x, be0.y - mean * s2[u][0].y};
            t2[u][1] = (f2_t){be0.z - mean * s2[u][1].x, be0.w - mean * s2[u][1].y};
            t2[u][2] = (f2_t){be1.x - mean * s2[u][2].x, be1.y - mean * s2[u][2].y};
            t2[u][3] = (f2_t){be1.z - mean * s2[u][3].x, be1.w - mean * s2[u][3].y};
        }
    }

    f4_t acc[4][2];                    // [m: 4 x 16px][n: 2 x 16co]
#pragma unroll
    for (int m = 0; m < 4; ++m)
#pragma unroll
        for (int n = 0; n < 2; ++n) acc[m][n] = (f4_t){0.f,0.f,0.f,0.f};

    uint4 q[4][4];     // [corner][u]
    float cw0, cw1, cw2, cw3;

    auto gload = [&](int tap) {
        int ky = tap / 3, kx = tap - ky * 3;
        float2 of = *(const float2*)(offp + 2 * tap);
        float py  = of.x + (float)(gy - 1 + ky);
        float pxx = of.y + (float)(gx - 1 + kx);
        float y0f = floorf(py), x0f = floorf(pxx);
        float ly = py - y0f, lx = pxx - x0f;
        int y0 = (int)y0f, x0 = (int)x0f;
        int y1 = y0 + 1, x1 = x0 + 1;
        float wy0 = ((uint)y0 < 64u) ? (1.f - ly) : 0.f;
        float wy1 = ((uint)y1 < 64u) ? ly : 0.f;
        float wx0 = ((uint)x0 < 64u) ? (1.f - lx) : 0.f;
        float wx1 = ((uint)x1 < 64u) ? lx : 0.f;
        int y0c = min(max(y0, 0), 63), y1c = min(max(y1, 0), 63);
        int x0c = min(max(x0, 0), 63), x1c = min(max(x1, 0), 63);
        cw0 = wy0 * wx0; cw1 = wy0 * wx1; cw2 = wy1 * wx0; cw3 = wy1 * wx1;
        const ushort* s0 = xb + ((gbase + (y0c << 6) + x0c) << 8) + (gl << 3);
        const ushort* s1 = xb + ((gbase + (y0c << 6) + x1c) << 8) + (gl << 3);
        const ushort* s2p = xb + ((gbase + (y1c << 6) + x0c) << 8) + (gl << 3);
        const ushort* s3 = xb + ((gbase + (y1c << 6) + x1c) << 8) + (gl << 3);
#pragma unroll
        for (int u = 0; u < 4; ++u) {
            q[0][u] = *(const uint4*)(s0 + (u << 6));
            q[1][u] = *(const uint4*)(s1 + (u << 6));
            q[2][u] = *(const uint4*)(s2p + (u << 6));
            q[3][u] = *(const uint4*)(s3 + (u << 6));
        }
    };

    auto gstore = [&](int buf) {
        f2_t w0 = {cw0, cw0}, w1 = {cw1, cw1}, w2 = {cw2, cw2}, w3 = {cw3, cw3};
#pragma unroll
        for (int u = 0; u < 4; ++u) {
            uint4 q0 = q[0][u], q1 = q[1][u], q2 = q[2][u], q3 = q[3][u];
            auto nrm = [&](uint w, int j) -> f2_t {
                f2_t v = (f2_t){bflo(w), bfhi(w)};
                if (FUSE) {
                    v = s2[u][j] * v + t2[u][j];
                    v.x = fmaxf(v.x, 0.f);
                    v.y = fmaxf(v.y, 0.f);
                }
                return v;
            };
            f2_t a0 = w0 * nrm(q0.x,0) + w1 * nrm(q1.x,0) + w2 * nrm(q2.x,0) + w3 * nrm(q3.x,0);
            f2_t a1 = w0 * nrm(q0.y,1) + w1 * nrm(q1.y,1) + w2 * nrm(q2.y,1) + w3 * nrm(q3.y,1);
            f2_t a2 = w0 * nrm(q0.z,2) + w1 * nrm(q1.z,2) + w2 * nrm(q2.z,2) + w3 * nrm(q3.z,2);
            f2_t a3 = w0 * nrm(q0.w,3) + w1 * nrm(q1.w,3) + w2 * nrm(q2.w,3) + w3 * nrm(q3.w,3);
            uint4 o;
            o.x = pkrn(a0.x, a0.y); o.y = pkrn(a1.x, a1.y);
            o.z = pkrn(a2.x, a2.y); o.w = pkrn(a3.x, a3.y);
            int kblk = (u << 3) + gl;                        // 8-channel group 0..31
            int chunk = (kblk << 6) + (gpx ^ (kblk & 7));    // XOR swizzle, 64-row tile
            *(uint4*)&As[buf][chunk << 3] = o;
        }
    };

    auto gemm = [&](int tap, int buf) {
        const ushort* wbase = wT + ((tap << 8) + (wave << 5) + lr) * 256 + (lq << 3);
        bfrag_t bf0[8], bf1[8];
#pragma unroll
        for (int s = 0; s < 8; ++s) {
            bf0[s] = *(const bfrag_t*)(wbase + (s << 5));
            bf1[s] = *(const bfrag_t*)(wbase + (16 << 8) + (s << 5));
        }
#pragma unroll
        for (int s = 0; s < 8; ++s) {
            int kblk = (s << 2) + lq;
            int kx7 = kblk & 7;
#pragma unroll
            for (int m = 0; m < 4; ++m) {
                int chunk = (kblk << 6) + (((m << 4) + lr) ^ kx7);
                bfrag_t a = *(const bfrag_t*)&As[buf][chunk << 3];
                acc[m][0] = __builtin_amdgcn_mfma_f32_16x16x32_bf16(a, bf0[s], acc[m][0], 0, 0, 0);
                acc[m][1] = __builtin_amdgcn_mfma_f32_16x16x32_bf16(a, bf1[s], acc[m][1], 0, 0, 0);
            }
        }
    };

    gload(0);
    gstore(0);
    __syncthreads();
    for (int tap = 0; tap < 9; ++tap) {
        if (tap < 8) gload(tap + 1);           // loads in flight during gemm
        gemm(tap, tap & 1);
        if (tap < 8) gstore((tap + 1) & 1);    // combine + LDS write after gemm
        __syncthreads();
    }

    // Epilogue: GN stats from regs + stage C tile in LDS (As[0] = exactly 32KB),
    // then coalesced dwordx4 copy-out (full 64B lines -> no RMW amplification).
    int cob = wave << 5;
#pragma unroll
    for (int n = 0; n < 2; ++n) {
        int co = cob + (n << 4) + lr;
        float s = 0.f, s2v = 0.f;
#pragma unroll
        for (int m = 0; m < 4; ++m)
#pragma unroll
            for (int r = 0; r < 4; ++r) {
                float v = acc[m][n][r];
                s += v; s2v += v * v;
                As[0][(((m << 4) + (lq << 2) + r) << 8) + co] = (short)f2bf(v);
            }
        int g = co >> 3;
        atomicAdd(&red[g], s);
        atomicAdd(&red[32 + g], s2v);
    }
    __syncthreads();
    {
        const uint4* src = (const uint4*)&As[0][0];
        uint4* dst = (uint4*)&outb[px0 << 8];
#pragma unroll
        for (int i = 0; i < 4; ++i)
            dst[tid + (i << 9)] = src[tid + (i << 9)];
    }
    if (tid < 32) {
        atomicAdd(&gnacc[((bb << 5) + tid) * 2], red[tid]);
        atomicAdd(&gnacc[((bb << 5) + tid) * 2 + 1], red[32 + tid]);
    }
}

// NHWC bf16 -> NCHW with fused GN2 + residual + ReLU. stats from raw sums.
__global__ __launch_bounds__(256) void final_bf16(const ushort* __restrict__ v2, const float* __restrict__ gnacc,
                                                  const float* __restrict__ gamma, const float* __restrict__ beta,
                                                  const float* __restrict__ xin, float* __restrict__ out) {
    __shared__ float lds[64][65];
    int bid = blockIdx.x;
    int cb = bid & 3, y = (bid >> 2) & 63, b = bid >> 8;
    int c0 = cb << 6;
    int tid = threadIdx.x;
#pragma unroll
    for (int i = 0; i < 4; ++i) {
        int q = tid + (i << 8);
        int x_l = q >> 4, c4 = (q & 15) << 2;
        s4_t v = *(const s4_t*)&v2[(((b << 12) + (y << 6) + x_l) << 8) + c0 + c4];
        lds[c4 + 0][x_l] = bf2f((ushort)v.x); lds[c4 + 1][x_l] = bf2f((ushort)v.y);
        lds[c4 + 2][x_l] = bf2f((ushort)v.z); lds[c4 + 3][x_l] = bf2f((ushort)v.w);
    }
    __syncthreads();
#pragma unroll
    for (int i = 0; i < 4; ++i) {
        int q = tid + (i << 8);
        int c_l = q >> 4, x4 = (q & 15) << 2;
        int c = c0 + c_l;
        int g = c >> 3;
        float2 a = *(const float2*)(gnacc + ((b << 5) + g) * 2);
        float mean = a.x * (1.f / 32768.f);
        float var = fmaxf(a.y * (1.f / 32768.f) - mean * mean, 0.f);
        float rstd = rsqrtf(var + EPSV);
        float ga = gamma[c], be = beta[c];
        const float* xp = &xin[((b << 8) + c) * 4096 + (y << 6) + x4];
        float4 r = ld4(xp);
        float4 o;
        o.x = fmaxf((lds[c_l][x4 + 0] - mean) * rstd * ga + be + r.x, 0.f);
        o.y = fmaxf((lds[c_l][x4 + 1] - mean) * rstd * ga + be + r.y, 0.f);
        o.z = fmaxf((lds[c_l][x4 + 2] - mean) * rstd * ga + be + r.z, 0.f);
        o.w = fmaxf((lds[c_l][x4 + 3] - mean) * rstd * ga + be + r.w, 0.f);
        st4(&out[((b << 8) + c) * 4096 + (y << 6) + x4], o);
    }
}

extern "C" void kernel_launch(void* const* d_in, const int* in_sizes, int n_in,
                              void* d_out, int out_size, void* d_ws, size_t ws_size,
                              hipStream_t stream) {
    (void)in_sizes; (void)n_in; (void)out_size; (void)ws_size;
    const float* x      = (const float*)d_in[0];
    const float* w_off1 = (const float*)d_in[1];
    const float* b_off1 = (const float*)d_in[2];
    const float* w_off2 = (const float*)d_in[3];
    const float* b_off2 = (const float*)d_in[4];
    const float* w_def1 = (const float*)d_in[5];
    const float* w_def2 = (const float*)d_in[6];
    const float* gamma1 = (const float*)d_in[7];
    const float* beta1  = (const float*)d_in[8];
    const float* gamma2 = (const float*)d_in[9];
    const float* beta2  = (const float*)d_in[10];
    float* out = (float*)d_out;

    float* ws = (float*)d_ws;
    float*  xb_f   = ws;                      // 2,097,152 floats (8MB bf16): xb / v2b
    float*  xb2_f  = xb_f + 2097152;          // (unused after GN fusion)
    float*  wT1_f  = xb2_f + 2097152;         // 294,912
    float*  wT2_f  = wT1_f + 294912;          // 294,912
    float*  wO1_f  = wT2_f + 294912;          // 36,864
    float*  wO2_f  = wO1_f + 36864;           // 36,864
    float*  offb   = wO2_f + 36864;           // 294,912 (16384 x 18)
    float*  gnacc1 = offb + 294912;           // 256
    float*  gnacc2 = gnacc1 + 256;            // 256 (contiguous 512 with gnacc1)

    ushort* xb  = (ushort*)xb_f;
    ushort* v2b = (ushort*)xb_f;
    ushort* wT1 = (ushort*)wT1_f;
    ushort* wT2 = (ushort*)wT2_f;
    ushort* wO1 = (ushort*)wO1_f;
    ushort* wO2 = (ushort*)wO2_f;
    ushort* t1b = (ushort*)d_out;             // stage-1 deform out (bf16) parked in d_out

    prep_all<<<1600, 256, 0, stream>>>(w_def1, w_def2, w_off1, w_off2, x,
                                       wT1, wT2, wO1, wO2, xb, gnacc1);
    offconv8<0><<<256, 512, 0, stream>>>(xb, nullptr, nullptr, nullptr, wO1, b_off1, offb);
    deform_mfma<0><<<256, 512, 0, stream>>>(xb, nullptr, nullptr, nullptr, offb, wT1, t1b, gnacc1);
    offconv8<1><<<256, 512, 0, stream>>>(t1b, gnacc1, gamma1, beta1, wO2, b_off2, offb);
    deform_mfma<1><<<256, 512, 0, stream>>>(t1b, gnacc1, gamma1, beta1, offb, wT2, v2b, gnacc2);
    final_bf16<<<1024, 256, 0, stream>>>(v2b, gnacc2, gamma2, beta2, x, out);
}

// Round 10
// 241.094 us; speedup vs baseline: 1.0117x; 1.0117x over previous
//
#include <hip/hip_runtime.h>
#include <hip/hip_bf16.h>

typedef unsigned int uint;
typedef unsigned short ushort;
typedef __attribute__((ext_vector_type(8))) short bfrag_t;
typedef __attribute__((ext_vector_type(4))) short s4_t;
typedef __attribute__((ext_vector_type(4))) float f4_t;
typedef __attribute__((ext_vector_type(2))) float f2_t;

#define EPSV 1e-5f

__device__ __forceinline__ float4 ld4(const float* p) { return *(const float4*)p; }
__device__ __forceinline__ void st4(float* p, float4 v) { *(float4*)p = v; }

__device__ __forceinline__ ushort f2bf(float f) {
    union { float f; uint u; } v; v.f = f;
    uint r = v.u + 0x7fffu + ((v.u >> 16) & 1u);
    return (ushort)(r >> 16);
}
__device__ __forceinline__ float bf2f(ushort s) {
    union { uint u; float f; } v; v.u = ((uint)s) << 16;
    return v.f;
}
__device__ __forceinline__ float bfhi(uint u) { union { uint u; float f; } v; v.u = u & 0xffff0000u; return v.f; }
__device__ __forceinline__ float bflo(uint u) { union { uint u; float f; } v; v.u = u << 16; return v.f; }
__device__ __forceinline__ uint pk2(float a, float b) { return (uint)f2bf(a) | ((uint)f2bf(b) << 16); }
__device__ __forceinline__ uint pkrn(float a, float b) {
    union { __hip_bfloat162 h; uint u; } v;
    v.h = __float22bfloat162_rn(make_float2(a, b));
    return v.u;
}

// One dispatch for all preprocessing:
//   bid <  512: wT[(k*256+co)*256+ci] = bf16(w_def[co][ci][k])
//   512..575  : wO[(k*32+co)*256+ci]  = co<18 ? bf16(w_off[co][ci][k]) : 0  (+ gnacc zeroing)
//   bid >= 576: NCHW fp32 -> NHWC bf16 transpose (1024 blocks)
__global__ __launch_bounds__(256) void prep_all(const float* __restrict__ wd1, const float* __restrict__ wd2,
                                                const float* __restrict__ wo1, const float* __restrict__ wo2,
                                                const float* __restrict__ x,
                                                ushort* __restrict__ oT1, ushort* __restrict__ oT2,
                                                ushort* __restrict__ oO1, ushort* __restrict__ oO2,
                                                ushort* __restrict__ xb, float* __restrict__ gnacc) {
    __shared__ float lds[64][65];
    int bid = blockIdx.x;
    int tid = threadIdx.x;
    if (bid < 512) {
        int co = bid & 255;
        int sel = bid >> 8;
        const float* w = sel ? wd2 : wd1;
        ushort* o = sel ? oT2 : oT1;
        const float* p = w + (co * 256 + tid) * 9;
        float v[9];
#pragma unroll
        for (int k = 0; k < 9; ++k) v[k] = p[k];
#pragma unroll
        for (int k = 0; k < 9; ++k) o[(k * 256 + co) * 256 + tid] = f2bf(v[k]);
    } else if (bid < 576) {
        int idx = bid - 512;
        int co = idx & 31;
        int sel = idx >> 5;
        const float* w = sel ? wo2 : wo1;
        ushort* o = sel ? oO2 : oO1;
        float v[9] = {0.f,0.f,0.f,0.f,0.f,0.f,0.f,0.f,0.f};
        if (co < 18) {
            const float* p = w + (co * 256 + tid) * 9;
#pragma unroll
            for (int k = 0; k < 9; ++k) v[k] = p[k];
        }
#pragma unroll
        for (int k = 0; k < 9; ++k) o[(k * 32 + co) * 256 + tid] = f2bf(v[k]);
        if (idx == 0) { gnacc[tid] = 0.f; gnacc[256 + tid] = 0.f; }
    } else {
        int b2 = bid - 576;                 // b*256 + y*4 + cb
        int cb = b2 & 3, y = (b2 >> 2) & 63, b = b2 >> 8;
        int c0 = cb << 6;
#pragma unroll
        for (int i = 0; i < 4; ++i) {
            int q = tid + (i << 8);
            int c_l = q >> 4, x4 = (q & 15) << 2;
            float4 v = ld4(&x[((b * 256 + c0 + c_l) << 12) + (y << 6) + x4]);
            lds[c_l][x4 + 0] = v.x; lds[c_l][x4 + 1] = v.y; lds[c_l][x4 + 2] = v.z; lds[c_l][x4 + 3] = v.w;
        }
        __syncthreads();
#pragma unroll
        for (int i = 0; i < 4; ++i) {
            int q = tid + (i << 8);
            int x_l = q >> 4, c4 = (q & 15) << 2;
            s4_t v;
            v.x = (short)f2bf(lds[c4 + 0][x_l]); v.y = (short)f2bf(lds[c4 + 1][x_l]);
            v.z = (short)f2bf(lds[c4 + 2][x_l]); v.w = (short)f2bf(lds[c4 + 3][x_l]);
            *(s4_t*)&xb[(((b << 12) + (y << 6) + x_l) << 8) + c0 + c4] = v;
        }
    }
}

// Fused offset-conv + deformable-conv stage. One block = one 64-px image row,
// grid 256 (same tile map as r8/r9). Phase A computes the 18 offset channels
// for this row into LDS (offs[64][18]) via the r8 k-split offconv; Phase B is
// the r6-frozen deform schedule reading offsets from LDS instead of global.
// Removes 2 dispatches + the offb global round-trip. LDS pool overlays
// phase-A red2 (67.6KB) with phase-B As (64KB); offs+red live beside (72.4KB).
// FUSE=1: both phases apply GN1+ReLU on t1b loads (r9 mechanism, 8ch=1 group).
template<int FUSE>
__global__ __launch_bounds__(512, 2) void stage(const ushort* __restrict__ xb, const float* __restrict__ gnin,
                                                const float* __restrict__ gamma, const float* __restrict__ beta,
                                                const ushort* __restrict__ wO, const float* __restrict__ obias,
                                                const ushort* __restrict__ wT, ushort* __restrict__ outb,
                                                float* __restrict__ gnacc) {
    __shared__ __align__(16) char pool[8 * 64 * 33 * 4];   // 67584 B: red2 (A) / As (B)
    __shared__ float offs[64][18];
    __shared__ float red[64];

    typedef float Red2Row[64][33];
    Red2Row* red2 = (Red2Row*)pool;                        // [8][64][33]
    short (*As)[16384] = (short(*)[16384])pool;            // [2][16384]

    int bidx = blockIdx.x;                  // 256
    int tile = (bidx & 7) * 32 + (bidx >> 3);   // XCD-contiguous px regions
    int px0 = tile << 6;
    int b = tile >> 6;                      // tile = b*64 + y
    int y = tile & 63;
    int bb = b;

    int tid = threadIdx.x;
    int wave = tid >> 6, lane = tid & 63;
    int lr = lane & 15, lq = lane >> 4;

    // ---------------- Phase A: offset conv -> offs[64][18] (LDS) ----------------
    {
        int cio = (wave << 5) + (lq << 3);  // this lane's 8-ci offset within 256

        float s8[8], t8[8];
        if (FUSE) {
            int g = cio >> 3;               // 8 ch/group
            float2 a = *(const float2*)(gnin + ((b << 5) + g) * 2);
            float mean = a.x * (1.f / 32768.f);
            float var = fmaxf(a.y * (1.f / 32768.f) - mean * mean, 0.f);
            float rstd = rsqrtf(var + EPSV);
#pragma unroll
            for (int j = 0; j < 8; ++j) {
                s8[j] = gamma[cio + j] * rstd;
                t8[j] = beta[cio + j] - mean * s8[j];
            }
        }

        f4_t acc[4][2];
#pragma unroll
        for (int m = 0; m < 4; ++m)
#pragma unroll
            for (int n = 0; n < 2; ++n) acc[m][n] = (f4_t){0.f,0.f,0.f,0.f};

#pragma unroll
        for (int tap = 0; tap < 9; ++tap) {
            int ky = tap / 3, kx = tap - ky * 3;
            int yy = y + ky - 1;
            if ((uint)yy < 64u) {           // wave-uniform row validity
                const ushort* wrow = wO + ((tap << 5) << 8) + cio;
                bfrag_t b0 = *(const bfrag_t*)(wrow + (lr << 8));
                bfrag_t b1 = *(const bfrag_t*)(wrow + ((16 + lr) << 8));
                const ushort* arow = xb + (((b << 6) + yy) << 14) + cio;   // row base (x=0)
#pragma unroll
                for (int m = 0; m < 4; ++m) {
                    int xx = (m << 4) + lr + kx - 1;
                    bfrag_t afr = (bfrag_t){0,0,0,0,0,0,0,0};
                    if ((uint)xx < 64u) {
                        if (FUSE) {
                            uint4 raw = *(const uint4*)(arow + (xx << 8));
                            union { uint4 u; bfrag_t f; } cv;
                            cv.u.x = pkrn(fmaxf(s8[0]*bflo(raw.x)+t8[0], 0.f), fmaxf(s8[1]*bfhi(raw.x)+t8[1], 0.f));
                            cv.u.y = pkrn(fmaxf(s8[2]*bflo(raw.y)+t8[2], 0.f), fmaxf(s8[3]*bfhi(raw.y)+t8[3], 0.f));
                            cv.u.z = pkrn(fmaxf(s8[4]*bflo(raw.z)+t8[4], 0.f), fmaxf(s8[5]*bfhi(raw.z)+t8[5], 0.f));
                            cv.u.w = pkrn(fmaxf(s8[6]*bflo(raw.w)+t8[6], 0.f), fmaxf(s8[7]*bfhi(raw.w)+t8[7], 0.f));
                            afr = cv.f;
                        } else {
                            afr = *(const bfrag_t*)(arow + (xx << 8));
                        }
                    }
                    acc[m][0] = __builtin_amdgcn_mfma_f32_16x16x32_bf16(afr, b0, acc[m][0], 0, 0, 0);
                    acc[m][1] = __builtin_amdgcn_mfma_f32_16x16x32_bf16(afr, b1, acc[m][1], 0, 0, 0);
                }
            }
        }
#pragma unroll
        for (int m = 0; m < 4; ++m)
#pragma unroll
            for (int n = 0; n < 2; ++n)
#pragma unroll
                for (int r = 0; r < 4; ++r)
                    red2[wave][lane][(m << 3) + (n << 2) + r] = acc[m][n][r];
        __syncthreads();
#pragma unroll
        for (int e = 0; e < 4; ++e) {
            int oi = tid + (e << 9);        // 0..2047 = 64px x 32co
            int px = oi >> 5, co = oi & 31;
            int m = px >> 4, w4 = px & 15;
            int lanes = ((w4 >> 2) << 4) + (co & 15);
            int elem = (m << 3) + ((co >> 4) << 2) + (w4 & 3);
            float v = 0.f;
#pragma unroll
            for (int w = 0; w < 8; ++w) v += red2[w][lanes][elem];
            if (co < 18) offs[px][co] = v + obias[co];
        }
        if (tid < 64) red[tid] = 0.f;
        __syncthreads();                    // offs visible; red2 reads done -> As may overwrite pool
    }

    // ---------------- Phase B: deformable conv (r6-frozen schedule) ----------------
    // gather role: 8 lanes per pixel (64 px x 8 = 512 thr)
    int gpx = tid >> 3;                // 0..63
    int gl = tid & 7;                  // 16B lane within 128B segment
    int pxg = px0 + gpx;
    int gy = (pxg >> 6) & 63, gx = pxg & 63;
    int gbase = (pxg >> 12) << 12;

    // fused-GN constants: q[corner][u] covers channels u*64+gl*8 .. +8 = group u*8+gl
    f2_t s2[4][4], t2[4][4];
    if (FUSE) {
#pragma unroll
        for (int u = 0; u < 4; ++u) {
            int g = (u << 3) + gl;
            float2 a = *(const float2*)(gnin + ((bb << 5) + g) * 2);
            float mean = a.x * (1.f / 32768.f);
            float var = fmaxf(a.y * (1.f / 32768.f) - mean * mean, 0.f);
            float rstd = rsqrtf(var + EPSV);
            int c0 = (u << 6) + (gl << 3);
            float4 ga0 = ld4(&gamma[c0]), ga1 = ld4(&gamma[c0 + 4]);
            float4 be0 = ld4(&beta[c0]),  be1 = ld4(&beta[c0 + 4]);
            s2[u][0] = (f2_t){ga0.x * rstd, ga0.y * rstd};
            s2[u][1] = (f2_t){ga0.z * rstd, ga0.w * rstd};
            s2[u][2] = (f2_t){ga1.x * rstd, ga1.y * rstd};
            s2[u][3] = (f2_t){ga1.z * rstd, ga1.w * rstd};
            t2[u][0] = (f2_t){be0.x - mean * s2[u][0].x, be0.y - mean * s2[u][0].y};
            t2[u][1] = (f2_t){be0.z - mean * s2[u][1].x, be0.w - mean * s2[u][1].y};
            t2[u][2] = (f2_t){be1.x - mean * s2[u][2].x, be1.y - mean * s2[u][2].y};
            t2[u][3] = (f2_t){be1.z - mean * s2[u][3].x, be1.w - mean * s2[u][3].y};
        }
    }

    f4_t acc[4][2];                    // [m: 4 x 16px][n: 2 x 16co]
#pragma unroll
    for (int m = 0; m < 4; ++m)
#pragma unroll
        for (int n = 0; n < 2; ++n) acc[m][n] = (f4_t){0.f,0.f,0.f,0.f};

    uint4 q[4][4];     // [corner][u]
    float cw0, cw1, cw2, cw3;

    auto gload = [&](int tap) {
        int ky = tap / 3, kx = tap - ky * 3;
        float2 of = *(const float2*)&offs[gpx][2 * tap];   // LDS read (8B aligned: 72B row stride)
        float py  = of.x + (float)(gy - 1 + ky);
        float pxx = of.y + (float)(gx - 1 + kx);
        float y0f = floorf(py), x0f = floorf(pxx);
        float ly = py - y0f, lx = pxx - x0f;
        int y0 = (int)y0f, x0 = (int)x0f;
        int y1 = y0 + 1, x1 = x0 + 1;
        float wy0 = ((uint)y0 < 64u) ? (1.f - ly) : 0.f;
        float wy1 = ((uint)y1 < 64u) ? ly : 0.f;
        float wx0 = ((uint)x0 < 64u) ? (1.f - lx) : 0.f;
        float wx1 = ((uint)x1 < 64u) ? lx : 0.f;
        int y0c = min(max(y0, 0), 63), y1c = min(max(y1, 0), 63);
        int x0c = min(max(x0, 0), 63), x1c = min(max(x1, 0), 63);
        cw0 = wy0 * wx0; cw1 = wy0 * wx1; cw2 = wy1 * wx0; cw3 = wy1 * wx1;
        const ushort* p0 = xb + ((gbase + (y0c << 6) + x0c) << 8) + (gl << 3);
        const ushort* p1 = xb + ((gbase + (y0c << 6) + x1c) << 8) + (gl << 3);
        const ushort* p2 = xb + ((gbase + (y1c << 6) + x0c) << 8) + (gl << 3);
        const ushort* p3 = xb + ((gbase + (y1c << 6) + x1c) << 8) + (gl << 3);
#pragma unroll
        for (int u = 0; u < 4; ++u) {
            q[0][u] = *(const uint4*)(p0 + (u << 6));
            q[1][u] = *(const uint4*)(p1 + (u << 6));
            q[2][u] = *(const uint4*)(p2 + (u << 6));
            q[3][u] = *(const uint4*)(p3 + (u << 6));
        }
    };

    auto gstore = [&](int buf) {
        f2_t w0 = {cw0, cw0}, w1 = {cw1, cw1}, w2 = {cw2, cw2}, w3 = {cw3, cw3};
#pragma unroll
        for (int u = 0; u < 4; ++u) {
            uint4 q0 = q[0][u], q1 = q[1][u], q2 = q[2][u], q3 = q[3][u];
            auto nrm = [&](uint w, int j) -> f2_t {
                f2_t v = (f2_t){bflo(w), bfhi(w)};
                if (FUSE) {
                    v = s2[u][j] * v + t2[u][j];
                    v.x = fmaxf(v.x, 0.f);
                    v.y = fmaxf(v.y, 0.f);
                }
                return v;
            };
            f2_t a0 = w0 * nrm(q0.x,0) + w1 * nrm(q1.x,0) + w2 * nrm(q2.x,0) + w3 * nrm(q3.x,0);
            f2_t a1 = w0 * nrm(q0.y,1) + w1 * nrm(q1.y,1) + w2 * nrm(q2.y,1) + w3 * nrm(q3.y,1);
            f2_t a2 = w0 * nrm(q0.z,2) + w1 * nrm(q1.z,2) + w2 * nrm(q2.z,2) + w3 * nrm(q3.z,2);
            f2_t a3 = w0 * nrm(q0.w,3) + w1 * nrm(q1.w,3) + w2 * nrm(q2.w,3) + w3 * nrm(q3.w,3);
            uint4 o;
            o.x = pkrn(a0.x, a0.y); o.y = pkrn(a1.x, a1.y);
            o.z = pkrn(a2.x, a2.y); o.w = pkrn(a3.x, a3.y);
            int kblk = (u << 3) + gl;                        // 8-channel group 0..31
            int chunk = (kblk << 6) + (gpx ^ (kblk & 7));    // XOR swizzle, 64-row tile
            *(uint4*)&As[buf][chunk << 3] = o;
        }
    };

    auto gemm = [&](int tap, int buf) {
        const ushort* wbase = wT + ((tap << 8) + (wave << 5) + lr) * 256 + (lq << 3);
        bfrag_t bf0[8], bf1[8];
#pragma unroll
        for (int s = 0; s < 8; ++s) {
            bf0[s] = *(const bfrag_t*)(wbase + (s << 5));
            bf1[s] = *(const bfrag_t*)(wbase + (16 << 8) + (s << 5));
        }
#pragma unroll
        for (int s = 0; s < 8; ++s) {
            int kblk = (s << 2) + lq;
            int kx7 = kblk & 7;
#pragma unroll
            for (int m = 0; m < 4; ++m) {
                int chunk = (kblk << 6) + (((m << 4) + lr) ^ kx7);
                bfrag_t a = *(const bfrag_t*)&As[buf][chunk << 3];
                acc[m][0] = __builtin_amdgcn_mfma_f32_16x16x32_bf16(a, bf0[s], acc[m][0], 0, 0, 0);
                acc[m][1] = __builtin_amdgcn_mfma_f32_16x16x32_bf16(a, bf1[s], acc[m][1], 0, 0, 0);
            }
        }
    };

    gload(0);
    gstore(0);
    __syncthreads();
    for (int tap = 0; tap < 9; ++tap) {
        if (tap < 8) gload(tap + 1);           // loads in flight during gemm
        gemm(tap, tap & 1);
        if (tap < 8) gstore((tap + 1) & 1);    // combine + LDS write after gemm
        __syncthreads();
    }

    // Epilogue: GN stats from regs + stage C tile in LDS (As[0] = exactly 32KB),
    // then coalesced dwordx4 copy-out (full 64B lines -> no RMW amplification).
    int cob = wave << 5;
#pragma unroll
    for (int n = 0; n < 2; ++n) {
        int co = cob + (n << 4) + lr;
        float s = 0.f, s2v = 0.f;
#pragma unroll
        for (int m = 0; m < 4; ++m)
#pragma unroll
            for (int r = 0; r < 4; ++r) {
                float v = acc[m][n][r];
                s += v; s2v += v * v;
                As[0][(((m << 4) + (lq << 2) + r) << 8) + co] = (short)f2bf(v);
            }
        int g = co >> 3;
        atomicAdd(&red[g], s);
        atomicAdd(&red[32 + g], s2v);
    }
    __syncthreads();
    {
        const uint4* src = (const uint4*)&As[0][0];
        uint4* dst = (uint4*)&outb[px0 << 8];
#pragma unroll
        for (int i = 0; i < 4; ++i)
            dst[tid + (i << 9)] = src[tid + (i << 9)];
    }
    if (tid < 32) {
        atomicAdd(&gnacc[((bb << 5) + tid) * 2], red[tid]);
        atomicAdd(&gnacc[((bb << 5) + tid) * 2 + 1], red[32 + tid]);
    }
}

// NHWC bf16 -> NCHW with fused GN2 + residual + ReLU. stats from raw sums.
__global__ __launch_bounds__(256) void final_bf16(const ushort* __restrict__ v2, const float* __restrict__ gnacc,
                                                  const float* __restrict__ gamma, const float* __restrict__ beta,
                                                  const float* __restrict__ xin, float* __restrict__ out) {
    __shared__ float lds[64][65];
    int bid = blockIdx.x;
    int cb = bid & 3, y = (bid >> 2) & 63, b = bid >> 8;
    int c0 = cb << 6;
    int tid = threadIdx.x;
#pragma unroll
    for (int i = 0; i < 4; ++i) {
        int q = tid + (i << 8);
        int x_l = q >> 4, c4 = (q & 15) << 2;
        s4_t v = *(const s4_t*)&v2[(((b << 12) + (y << 6) + x_l) << 8) + c0 + c4];
        lds[c4 + 0][x_l] = bf2f((ushort)v.x); lds[c4 + 1][x_l] = bf2f((ushort)v.y);
        lds[c4 + 2][x_l] = bf2f((ushort)v.z); lds[c4 + 3][x_l] = bf2f((ushort)v.w);
    }
    __syncthreads();
#pragma unroll
    for (int i = 0; i < 4; ++i) {
        int q = tid + (i << 8);
        int c_l = q >> 4, x4 = (q & 15) << 2;
        int c = c0 + c_l;
        int g = c >> 3;
        float2 a = *(const float2*)(gnacc + ((b << 5) + g) * 2);
        float mean = a.x * (1.f / 32768.f);
        float var = fmaxf(a.y * (1.f / 32768.f) - mean * mean, 0.f);
        float rstd = rsqrtf(var + EPSV);
        float ga = gamma[c], be = beta[c];
        const float* xp = &xin[((b << 8) + c) * 4096 + (y << 6) + x4];
        float4 r = ld4(xp);
        float4 o;
        o.x = fmaxf((lds[c_l][x4 + 0] - mean) * rstd * ga + be + r.x, 0.f);
        o.y = fmaxf((lds[c_l][x4 + 1] - mean) * rstd * ga + be + r.y, 0.f);
        o.z = fmaxf((lds[c_l][x4 + 2] - mean) * rstd * ga + be + r.z, 0.f);
        o.w = fmaxf((lds[c_l][x4 + 3] - mean) * rstd * ga + be + r.w, 0.f);
        st4(&out[((b << 8) + c) * 4096 + (y << 6) + x4], o);
    }
}

extern "C" void kernel_launch(void* const* d_in, const int* in_sizes, int n_in,
                              void* d_out, int out_size, void* d_ws, size_t ws_size,
                              hipStream_t stream) {
    (void)in_sizes; (void)n_in; (void)out_size; (void)ws_size;
    const float* x      = (const float*)d_in[0];
    const float* w_off1 = (const float*)d_in[1];
    const float* b_off1 = (const float*)d_in[2];
    const float* w_off2 = (const float*)d_in[3];
    const float* b_off2 = (const float*)d_in[4];
    const float* w_def1 = (const float*)d_in[5];
    const float* w_def2 = (const float*)d_in[6];
    const float* gamma1 = (const float*)d_in[7];
    const float* beta1  = (const float*)d_in[8];
    const float* gamma2 = (const float*)d_in[9];
    const float* beta2  = (const float*)d_in[10];
    float* out = (float*)d_out;

    float* ws = (float*)d_ws;
    float*  xb_f   = ws;                      // 2,097,152 floats (8MB bf16): xb / v2b
    float*  xb2_f  = xb_f + 2097152;          // (unused)
    float*  wT1_f  = xb2_f + 2097152;         // 294,912
    float*  wT2_f  = wT1_f + 294912;          // 294,912
    float*  wO1_f  = wT2_f + 294912;          // 36,864
    float*  wO2_f  = wO1_f + 36864;           // 36,864
    float*  offb   = wO2_f + 36864;           // (unused after LDS fusion)
    float*  gnacc1 = offb + 294912;           // 256
    float*  gnacc2 = gnacc1 + 256;            // 256 (contiguous 512 with gnacc1)

    ushort* xb  = (ushort*)xb_f;
    ushort* v2b = (ushort*)xb_f;
    ushort* wT1 = (ushort*)wT1_f;
    ushort* wT2 = (ushort*)wT2_f;
    ushort* wO1 = (ushort*)wO1_f;
    ushort* wO2 = (ushort*)wO2_f;
    ushort* t1b = (ushort*)d_out;             // stage-1 deform out (bf16) parked in d_out

    prep_all<<<1600, 256, 0, stream>>>(w_def1, w_def2, w_off1, w_off2, x,
                                       wT1, wT2, wO1, wO2, xb, gnacc1);
    stage<0><<<256, 512, 0, stream>>>(xb, nullptr, nullptr, nullptr, wO1, b_off1, wT1, t1b, gnacc1);
    stage<1><<<256, 512, 0, stream>>>(t1b, gnacc1, gamma1, beta1, wO2, b_off2, wT2, v2b, gnacc2);
    final_bf16<<<1024, 256, 0, stream>>>(v2b, gnacc2, gamma2, beta2, x, out);
}